// Round 13
// baseline (2765.405 us; speedup 1.0000x reference)
//
#include <hip/hip_runtime.h>
#include <hip/hip_cooperative_groups.h>
#include <math.h>

namespace cg = cooperative_groups;

// Graph-diffusion, 10 steps of edge-scatter + node update.
//
// R11 post-mortem: step cost (57-60us) is invariant to occupancy, TPB, ILP,
// and gather-elimination across 4 structurally different designs => either a
// ~1.4TB/s stream characteristic or the 20 per-step kernel boundaries; step
// counters never visible (k_bucket replays own the top-5).
// R12/R13: (1) ALL 10 steps fused into ONE cooperative kernel (grid.sync
//      between phases) - deletes 20 launch/drain boundaries AND surfaces the
//      step loop's counters as the dominant dispatch. Synchronous error check
//      falls back to the R11 per-step loop.
//      (2) k_bucket staging buffer padded to odd word stride (129) so insert
//      banks depend on bin -> kills the 1.6M cross-bin conflicts.

#define MAXBINS     64
#define BIN_SHIFT   11
#define BIN_SIZE    2048      // 1 << BIN_SHIFT
#define STAGE_CAP   64        // LDS staging slots per bin (= wave width)
#define BUCKET_GRID 1024
#define BUCKET_TPB  256
#define BUCKET_K    8         // edges per thread per round
#define STEP_TPB    256

__global__ void k_detect(const unsigned long long* ei, int* flag) {
    if (blockIdx.x == 0 && threadIdx.x == 0) {
        // int64 indices (<2^17) have zero high words; int32 data read as u64
        // carries a random index in the high word (all-64-zero ~ never).
        int is64 = 1;
        for (int k = 0; k < 64; ++k)
            if ((ei[k] >> 32) != 0ULL) { is64 = 0; break; }
        *flag = is64;
    }
}

// scales + zero the global bucket cursors.
__global__ void k_scales(const float* __restrict__ time_decay,
                         const float* __restrict__ edge_weight,
                         float* __restrict__ step_scale, int num_steps,
                         unsigned int* __restrict__ gcur) {
    int i = threadIdx.x;
    if (i < num_steps) {
        float td = time_decay[i];
        step_scale[i] = edge_weight[i] * expf(-td * td);
    }
    if (i < MAXBINS) gcur[i] = 0u;
}

__global__ void k_init(const float* __restrict__ x, float* __restrict__ cur0,
                       float* __restrict__ surv, int n) {
    int i = blockIdx.x * blockDim.x + threadIdx.x;
    if (i < n) {
        float v = x[i];
        cur0[i] = v;
        surv[i] = 1.0f - v;
    }
}

// Single-pass bucketing: LDS staging (odd-stride padded rows), batched cursor
// reservation, per-wave-per-bin flush.
__global__ void k_bucket(const void* __restrict__ ei_raw, const int* __restrict__ flag,
                         const float* __restrict__ probs, unsigned int* __restrict__ gcur,
                         float2* __restrict__ sorted, unsigned int capr,
                         int E, int nbins) {
    __shared__ float buf[MAXBINS][2 * STAGE_CAP + 1];   // stride 129 words (odd)
    __shared__ unsigned int cnt[MAXBINS];
    __shared__ unsigned int gbase[MAXBINS];
    const int t = threadIdx.x;
    const int wid = t >> 6, lane = t & 63;
    const int nwaves = BUCKET_TPB / 64;
    const int is64 = *flag;
    const int chunk = (E + gridDim.x - 1) / gridDim.x;
    const int beg = blockIdx.x * chunk;
    const int end = min(E, beg + chunk);
    for (int i = t; i < nbins; i += BUCKET_TPB) cnt[i] = 0u;
    __syncthreads();
    const int ROUND = BUCKET_TPB * BUCKET_K;
    for (int rbeg = beg; rbeg < end; rbeg += ROUND) {
        // ---- insert phase ----
        for (int k = 0; k < BUCKET_K; ++k) {
            int e = rbeg + k * BUCKET_TPB + t;
            if (e < end) {
                int src, dst;
                if (is64) {
                    const long long* s = (const long long*)ei_raw;
                    src = (int)s[e]; dst = (int)s[e + E];
                } else {
                    const int* s = (const int*)ei_raw;
                    src = s[e]; dst = s[e + E];
                }
                float pr = probs[e];
                int bin = dst >> BIN_SHIFT;
                unsigned int payload = (unsigned int)src |
                                       ((unsigned int)(dst & (BIN_SIZE - 1)) << 17);
                unsigned int pos = atomicAdd(&cnt[bin], 1u);
                if (pos < STAGE_CAP) {
                    buf[bin][2 * pos]     = __uint_as_float(payload);
                    buf[bin][2 * pos + 1] = pr;
                } else {
                    // rare overflow: direct per-edge reservation (guarded)
                    unsigned int gp = atomicAdd(&gcur[bin], 1u);
                    if (gp < capr)
                        sorted[(size_t)bin * capr + gp] =
                            make_float2(__uint_as_float(payload), pr);
                }
            }
        }
        __syncthreads();
        // ---- batched reservation: one thread per bin ----
        if (t < nbins) {
            unsigned int c = min(cnt[t], (unsigned int)STAGE_CAP);
            if (c > 0u) gbase[t] = atomicAdd(&gcur[t], c);
        }
        __syncthreads();
        // ---- flush: one bin per wave per iter; lane l writes element l ----
        for (int b = wid; b < nbins; b += nwaves) {
            unsigned int c = min(cnt[b], (unsigned int)STAGE_CAP);
            if ((unsigned int)lane < c) {
                unsigned int gp = gbase[b] + (unsigned int)lane;
                if (gp < capr)
                    sorted[(size_t)b * capr + gp] =
                        make_float2(buf[b][2 * lane], buf[b][2 * lane + 1]);
            }
        }
        __syncthreads();
        for (int i = t; i < nbins; i += BUCKET_TPB) cnt[i] = 0u;
        __syncthreads();
    }
}

// Fused 10-step loop (cooperative). Phase A = R11's k_step body; grid.sync;
// Phase B = R11's k_reduce body; grid.sync. No early returns (coop-safe).
__global__ void __launch_bounds__(STEP_TPB)
k_steps(const float2* __restrict__ sorted, const unsigned int* __restrict__ gcur,
        float* __restrict__ bufA, float* __restrict__ bufB,
        float* __restrict__ surv, float* __restrict__ part,
        const float* __restrict__ step_scale, const float* __restrict__ bias_p,
        float* __restrict__ out,
        unsigned int capr, int pstride, int splits, int n, int S) {
    cg::grid_group grid = cg::this_grid();
    __shared__ float acc[BIN_SIZE];
    const int bid = blockIdx.x, t = threadIdx.x;
    const int bin = bid / splits;
    const int sp  = bid - bin * splits;
    const unsigned int cntv = min(gcur[bin], capr);
    unsigned int sub = ((cntv + (unsigned int)splits - 1) / (unsigned int)splits + 3u) & ~3u;
    const unsigned int s0 = min(cntv, (unsigned int)sp * sub);
    const unsigned int s1 = min(cntv, s0 + sub);
    const float2* base = sorted + (size_t)bin * capr;
    float* dstp = part + (size_t)sp * pstride + (size_t)bin * BIN_SIZE;
    const int gsz = (int)gridDim.x * STEP_TPB;
    for (int s = 0; s < S; ++s) {
        const float* cur_in = (s & 1) ? bufB : bufA;
        float*       cur_out = (s & 1) ? bufA : bufB;
        // ---- phase A: edge accumulation into LDS, write partial ----
        for (int i = t; i < BIN_SIZE; i += STEP_TPB) acc[i] = 0.0f;
        __syncthreads();
        for (unsigned int j = s0 + (unsigned int)t * 4u; j < s1; j += STEP_TPB * 4u) {
            if (j + 4u <= s1) {                   // aligned: s0%4==0, j%4==0
                float4 a = *reinterpret_cast<const float4*>(base + j);
                float4 b = *reinterpret_cast<const float4*>(base + j + 2);
                unsigned int k0 = __float_as_uint(a.x), k1 = __float_as_uint(a.z);
                unsigned int k2 = __float_as_uint(b.x), k3 = __float_as_uint(b.z);
                float m0 = cur_in[k0 & 0x1FFFFu] * a.y;
                float m1 = cur_in[k1 & 0x1FFFFu] * a.w;
                float m2 = cur_in[k2 & 0x1FFFFu] * b.y;
                float m3 = cur_in[k3 & 0x1FFFFu] * b.w;
                atomicAdd(&acc[k0 >> 17], m0);
                atomicAdd(&acc[k1 >> 17], m1);
                atomicAdd(&acc[k2 >> 17], m2);
                atomicAdd(&acc[k3 >> 17], m3);
            } else {
                for (unsigned int q = j; q < s1; ++q) {
                    float2 kp = base[q];
                    unsigned int k = __float_as_uint(kp.x);
                    atomicAdd(&acc[k >> 17], cur_in[k & 0x1FFFFu] * kp.y);
                }
            }
        }
        __syncthreads();
        for (int i = t; i < BIN_SIZE; i += STEP_TPB) dstp[i] = acc[i];
        grid.sync();
        // ---- phase B: reduce partials, node update ----
        const float scale = step_scale[s];
        const float bias  = bias_p[0];
        const int last = (s == S - 1);
        for (int i = bid * STEP_TPB + t; i < n; i += gsz) {
            float c = 0.0f;
            for (int r = 0; r < splits; ++r) c += part[(size_t)r * pstride + i];
            c = c * scale + bias;
            cur_out[i] = c;
            float sv = surv[i] * (1.0f - c);
            surv[i] = sv;
            if (last) out[i] = fminf(fmaxf(1.0f - sv, 0.0f), 1.0f);
        }
        grid.sync();
    }
}

// --- non-cooperative fallback step pair (R11, proven) ---
__global__ void __launch_bounds__(STEP_TPB)
k_step(const float2* __restrict__ sorted, const unsigned int* __restrict__ gcur,
       const float* __restrict__ cur_in, float* __restrict__ part,
       unsigned int capr, int pstride, int nbins, int splits) {
    __shared__ float acc[BIN_SIZE];
    const int bin = blockIdx.x / splits;
    const int sp  = blockIdx.x - bin * splits;
    const int t = threadIdx.x;
    for (int i = t; i < BIN_SIZE; i += STEP_TPB) acc[i] = 0.0f;
    __syncthreads();
    unsigned int cntv = min(gcur[bin], capr);
    unsigned int sub = ((cntv + (unsigned int)splits - 1) / (unsigned int)splits + 3u) & ~3u;
    unsigned int s0 = min(cntv, (unsigned int)sp * sub);
    unsigned int s1 = min(cntv, s0 + sub);
    const float2* base = sorted + (size_t)bin * capr;
    for (unsigned int j = s0 + (unsigned int)t * 4u; j < s1; j += STEP_TPB * 4u) {
        if (j + 4u <= s1) {
            float4 a = *reinterpret_cast<const float4*>(base + j);
            float4 b = *reinterpret_cast<const float4*>(base + j + 2);
            unsigned int k0 = __float_as_uint(a.x), k1 = __float_as_uint(a.z);
            unsigned int k2 = __float_as_uint(b.x), k3 = __float_as_uint(b.z);
            atomicAdd(&acc[k0 >> 17], cur_in[k0 & 0x1FFFFu] * a.y);
            atomicAdd(&acc[k1 >> 17], cur_in[k1 & 0x1FFFFu] * a.w);
            atomicAdd(&acc[k2 >> 17], cur_in[k2 & 0x1FFFFu] * b.y);
            atomicAdd(&acc[k3 >> 17], cur_in[k3 & 0x1FFFFu] * b.w);
        } else {
            for (unsigned int q = j; q < s1; ++q) {
                float2 kp = base[q];
                unsigned int k = __float_as_uint(kp.x);
                atomicAdd(&acc[k >> 17], cur_in[k & 0x1FFFFu] * kp.y);
            }
        }
    }
    __syncthreads();
    float* dst = part + (size_t)sp * pstride + (size_t)bin * BIN_SIZE;
    for (int i = t; i < BIN_SIZE; i += STEP_TPB)
        dst[i] = acc[i];
}

__global__ void k_reduce(const float* __restrict__ part, int pstride, int splits,
                         float* __restrict__ cur_out, float* __restrict__ surv,
                         const float* __restrict__ step_scale, const float* __restrict__ bias_p,
                         float* __restrict__ out, int step, int n, int last) {
    int i = blockIdx.x * blockDim.x + threadIdx.x;
    if (i >= n) return;
    float c = 0.0f;
    for (int s = 0; s < splits; ++s) c += part[(size_t)s * pstride + i];
    c = c * step_scale[step] + bias_p[0];
    cur_out[i] = c;
    float sv = surv[i] * (1.0f - c);
    surv[i] = sv;
    if (last) out[i] = fminf(fmaxf(1.0f - sv, 0.0f), 1.0f);
}

// --- minimal fallback (ws too small / n too big; not expected) ---
__global__ void k_init0(const float* __restrict__ x, float* __restrict__ cur,
                        float* __restrict__ surv, float* __restrict__ acc, int n) {
    int i = blockIdx.x * blockDim.x + threadIdx.x;
    if (i < n) {
        float v = x[i];
        cur[i] = v; surv[i] = 1.0f - v; acc[i] = 0.0f;
    }
}

__global__ void k_edge_raw(const void* __restrict__ ei_raw, const int* __restrict__ flag,
                           const float* __restrict__ probs, const float* __restrict__ cur,
                           float* __restrict__ acc, const float* __restrict__ step_scale,
                           int step, int num_edges) {
    const float scale = step_scale[step];
    const int is64 = *flag;
    const int stride = gridDim.x * blockDim.x;
    for (int e = blockIdx.x * blockDim.x + threadIdx.x; e < num_edges; e += stride) {
        int src, dst;
        if (is64) {
            const long long* s = (const long long*)ei_raw;
            src = (int)s[e]; dst = (int)s[e + num_edges];
        } else {
            const int* s = (const int*)ei_raw;
            src = s[e]; dst = s[e + num_edges];
        }
        atomicAdd(&acc[dst], cur[src] * (probs[e] * scale));
    }
}

__global__ void k_node(float* __restrict__ cur, float* __restrict__ acc,
                       float* __restrict__ surv, const float* __restrict__ bias_p,
                       float* __restrict__ out, int n, int write_out) {
    int i = blockIdx.x * blockDim.x + threadIdx.x;
    if (i < n) {
        float c = acc[i] + bias_p[0];
        acc[i] = 0.0f;
        cur[i] = c;
        float s = surv[i] * (1.0f - c);
        surv[i] = s;
        if (write_out) out[i] = fminf(fmaxf(1.0f - s, 0.0f), 1.0f);
    }
}

static inline size_t al256(size_t x) { return (x + 255) & ~(size_t)255; }

extern "C" void kernel_launch(void* const* d_in, const int* in_sizes, int n_in,
                              void* d_out, int out_size, void* d_ws, size_t ws_size,
                              hipStream_t stream) {
    const float* x           = (const float*)d_in[0];
    const void*  ei          = d_in[1];
    const float* probs       = (const float*)d_in[2];
    const float* time_decay  = (const float*)d_in[3];
    const float* node_bias   = (const float*)d_in[4];
    const float* edge_weight = (const float*)d_in[5];
    float* outf = (float*)d_out;

    const int n = in_sizes[0];
    const int E = in_sizes[2];
    const int S = in_sizes[3];

    char* ws = (char*)d_ws;
    int*          flag       = (int*)ws;                    // 4B @ 0
    float*        step_scale = (float*)(ws + 64);           // S floats
    unsigned int* gcur       = (unsigned int*)(ws + 256);   // MAXBINS u32

    const int nbins   = (n + BIN_SIZE - 1) >> BIN_SHIFT;
    const int pstride = nbins * BIN_SIZE;

    // Bucket-region capacity: want mean+16sigma, accept down to mean+6sigma.
    const double   meand  = (double)E / (nbins > 0 ? nbins : 1);
    const double   sigma  = sqrt(meand > 1.0 ? meand : 1.0);
    unsigned int   want   = (unsigned int)(meand + 16.0 * sigma + 64.0);
    unsigned int   least  = (unsigned int)(meand + 6.0 * sigma + 64.0);
    want  = (want  + 63u) & ~63u;
    least = (least + 63u) & ~63u;

    const size_t nbA      = al256((size_t)n * 4);
    const size_t off_bufA = 512;
    const size_t off_bufB = off_bufA + nbA;
    const size_t off_surv = off_bufB + nbA;
    const size_t off_part = al256(off_surv + nbA);

    // Choose largest SPLITS whose layout fits with capr >= least.
    // Grid nbins*splits must stay co-resident for cooperative launch:
    // 256 thr + 8KB LDS -> 8 blocks/CU cap; keep grid <= 2048.
    int splits = 0;
    unsigned int capr = 0;
    size_t off_sort = 0;
    const int cand[3] = {16, 8, 4};
    for (int ci = 0; ci < 3; ++ci) {
        int sp = cand[ci];
        if ((long long)nbins * sp > 2048) continue;
        size_t part_b = (size_t)sp * pstride * 4;
        size_t osort  = al256(off_part + part_b);
        if (ws_size <= osort) continue;
        size_t availb = ws_size - osort;
        unsigned int acap = (unsigned int)((availb / ((size_t)nbins * 8)) & ~(size_t)63);
        if (acap >= least) {
            splits  = sp;
            capr    = acap < want ? acap : want;
            off_sort = osort;
            break;
        }
    }

    const int nthreads  = 256;
    const int node_grid = (n + nthreads - 1) / nthreads;

    const bool ok = (n <= (1 << 17)) && (nbins >= 1) && (nbins <= MAXBINS) &&
                    (E > 0) && (splits > 0);

    k_detect<<<1, 64, 0, stream>>>((const unsigned long long*)ei, flag);
    k_scales<<<1, 64, 0, stream>>>(time_decay, edge_weight, step_scale, S, gcur);

    if (!ok) {
        // Raw-atomic fallback: cur | surv | acc.
        float* cur  = (float*)(ws + off_bufA);
        float* surv = (float*)(ws + off_surv);
        float* acc  = (float*)(ws + off_bufB);
        k_init0<<<node_grid, nthreads, 0, stream>>>(x, cur, surv, acc, n);
        for (int s = 0; s < S; ++s) {
            k_edge_raw<<<2048, nthreads, 0, stream>>>(ei, flag, probs, cur, acc,
                                                      step_scale, s, E);
            k_node<<<node_grid, nthreads, 0, stream>>>(cur, acc, surv, node_bias,
                                                       outf, n, s == S - 1 ? 1 : 0);
        }
        return;
    }

    float*  bufA   = (float*)(ws + off_bufA);
    float*  bufB   = (float*)(ws + off_bufB);
    float*  surv   = (float*)(ws + off_surv);
    float*  part   = (float*)(ws + off_part);
    float2* sorted = (float2*)(ws + off_sort);

    k_init<<<node_grid, nthreads, 0, stream>>>(x, bufA, surv, n);

    k_bucket<<<BUCKET_GRID, BUCKET_TPB, 0, stream>>>(ei, flag, probs, gcur, sorted,
                                                     capr, E, nbins);

    const int step_grid = nbins * splits;

    // Cooperative fused loop; synchronous error => fall back to per-step loop.
    {
        const float2* a_sorted = sorted;
        const unsigned int* a_gcur = gcur;
        float* a_bufA = bufA; float* a_bufB = bufB;
        float* a_surv = surv; float* a_part = part;
        const float* a_ss = step_scale; const float* a_bias = node_bias;
        float* a_out = outf;
        unsigned int a_capr = capr;
        int a_pstride = pstride, a_splits = splits, a_n = n, a_S = S;
        void* args[] = {&a_sorted, &a_gcur, &a_bufA, &a_bufB, &a_surv, &a_part,
                        &a_ss, &a_bias, &a_out, &a_capr, &a_pstride, &a_splits,
                        &a_n, &a_S};
        hipError_t cerr = hipLaunchCooperativeKernel((const void*)k_steps,
                                                     dim3(step_grid), dim3(STEP_TPB),
                                                     args, 0, stream);
        if (cerr == hipSuccess) return;
    }

    // Fallback: per-step kernel pair (R11 structure).
    for (int s = 0; s < S; ++s) {
        float* ci = (s & 1) ? bufB : bufA;
        float* co = (s & 1) ? bufA : bufB;
        k_step<<<step_grid, STEP_TPB, 0, stream>>>(sorted, gcur, ci, part,
                                                   capr, pstride, nbins, splits);
        k_reduce<<<node_grid, nthreads, 0, stream>>>(part, pstride, splits, co, surv,
                                                     step_scale, node_bias, outf,
                                                     s, n, s == S - 1 ? 1 : 0);
    }
}